// Round 6
// baseline (38.465 us; speedup 1.0000x reference)
//
#include <hip/hip_runtime.h>

#define LOG2E 1.4426950408889634f
#define C1 (10.0f * LOG2E)

// ws layout (bytes):
//   xe [73984 float2] @ 0      : padded (x, E1=exp2(C1*x)), [b*16+ci][34][34], pad -> (0,1)
//   P4 [13824 float4] @ 591872 : [co][ci][j][nb] {T1=exp2(C1*Ec), Zk=2*LOG2E*k, A=Zk*Ec, W2=2*Ps*coef}
//   K0 [32 float]     @ 813056
__global__ __launch_bounds__(256) void prep_kernel(
    const float* __restrict__ x,
    const float* __restrict__ kk, const float* __restrict__ Ec,
    const float* __restrict__ Ps, const float* __restrict__ bias,
    const float* __restrict__ coef, const float* __restrict__ out_bias,
    float2* __restrict__ xe, float4* __restrict__ P4, float* __restrict__ K0) {
    const int bid = blockIdx.x, tid = threadIdx.x;
    if (bid < 289) {                       // 289*256 = 73984 = 64*34*34
        int i = bid * 256 + tid;
        int ch = i / 1156;
        int rem = i - ch * 1156;
        int r = rem / 34;
        int c = rem - r * 34;
        float xv = 0.f;
        if ((unsigned)(r - 1) < 32u && (unsigned)(c - 1) < 32u)
            xv = x[(ch << 10) + (r - 1) * 32 + (c - 1)];
        xe[i] = make_float2(xv, __builtin_amdgcn_exp2f(C1 * xv));
    } else if (bid < 343) {                // 54*256 = 13824 params
        int i = (bid - 289) * 256 + tid;
        int co = i / 432;
        int r  = i - co * 432;             // input layout [ci][nb][j]
        int ci = r / 27;
        int r2 = r - ci * 27;
        int nb = r2 / 9;
        int j  = r2 - nb * 9;
        int o  = ((co * 16 + ci) * 9 + j) * 3 + nb;
        float e  = Ec[i];
        float zk = 2.0f * LOG2E * kk[i];
        P4[o] = make_float4(__builtin_amdgcn_exp2f(C1 * e), zk, zk * e,
                            2.0f * Ps[i] * coef[i]);
    } else {                               // 8 blocks x 4 waves: K0 per co
        int co = (bid - 343) * 4 + (tid >> 6);
        int lane = tid & 63;
        float sum = 0.f;
        for (int j = lane; j < 432; j += 64) {
            int idx = co * 432 + j;
            sum += coef[idx] * (Ps[idx] + bias[idx]);
        }
        #pragma unroll
        for (int off = 32; off >= 1; off >>= 1) sum += __shfl_down(sum, off, 64);
        if (lane == 0) K0[co] = sum + out_bias[co];
    }
}

// grid 2048 = (b:4, co:32, chunk:16 of 2 rows); 4 waves; wave w owns ci [4w,4w+4).
// X window staged in LDS; one rcp per 3 terms (product trick) in both sigmoid phases.
__global__ __launch_bounds__(256, 8) void main_kernel(
    const float2* __restrict__ xe, const float4* __restrict__ P4,
    const float* __restrict__ K0, float* __restrict__ out) {
    __shared__ float2 sX[2176];   // [ci:16][r:4][c:34]
    __shared__ float red[256];
    const int bid = blockIdx.x, tid = threadIdx.x;
    const int chunk = bid & 15;
    const int co    = (bid >> 4) & 31;
    const int b     = bid >> 9;

    // cooperative stage: rows chunk*2 .. chunk*2+3 (padded coords) of all 16 ci
    for (int t = tid; t < 2176; t += 256) {
        int ci  = t / 136;
        int rem = t - ci * 136;
        int r   = rem / 34;
        int c   = rem - r * 34;
        sX[t] = xe[((b * 16 + ci) * 34 + chunk * 2 + r) * 34 + c];
    }
    __syncthreads();

    const int px = tid & 63;
    const int w  = px & 31;
    const int hr = px >> 5;                // 0..1
    const int cb = (tid >> 6) << 2;
    const float4* pk = P4 + (co * 16 + cb) * 27;

    float a0 = 0.f, a1 = 0.f, a2 = 0.f;
    #pragma unroll
    for (int i = 0; i < 4; ++i) {
        const float2* xw = &sX[(cb + i) * 136 + hr * 34 + w];
        const float4* pc = pk + i * 27;
        #pragma unroll
        for (int j = 0; j < 9; ++j) {
            const float2 X = xw[(j / 3) * 34 + (j % 3)];
            const float xv = X.x, E1 = X.y;
            const float4 P0 = pc[j * 3 + 0];
            const float4 P1 = pc[j * 3 + 1];
            const float4 P2 = pc[j * 3 + 2];
            // cn_i = 1/(1+E1*T1_i), one rcp for all three
            float d0 = fminf(__builtin_fmaf(E1, P0.x, 1.f), 0x1p25f);
            float d1 = fminf(__builtin_fmaf(E1, P1.x, 1.f), 0x1p25f);
            float d2 = fminf(__builtin_fmaf(E1, P2.x, 1.f), 0x1p25f);
            float q01 = d0 * d1, q12 = d1 * d2, q02 = d0 * d2;
            float rp  = __builtin_amdgcn_rcpf(q01 * d2);
            float rp2 = 0.2f * rp;         // folds the 0.2 factor: 0.2*cn_i = rp2*q_i
            float t0 = __builtin_fmaf(P0.y, xv, P0.z);
            float t1 = __builtin_fmaf(P1.y, xv, P1.z);
            float t2 = __builtin_fmaf(P2.y, xv, P2.z);
            float u0 = fminf(__builtin_fmaf(-P0.z, rp2 * q12, t0), 25.f);
            float u1 = fminf(__builtin_fmaf(-P1.z, rp2 * q02, t1), 25.f);
            float u2 = fminf(__builtin_fmaf(-P2.z, rp2 * q01, t2), 25.f);
            float e0 = __builtin_amdgcn_exp2f(u0);
            float e1 = __builtin_amdgcn_exp2f(u1);
            float e2 = __builtin_amdgcn_exp2f(u2);
            // r_i = 1/(1+e_i), one rcp for all three
            float f0 = 1.f + e0, f1 = 1.f + e1, f2 = 1.f + e2;
            float s01 = f0 * f1, s12 = f1 * f2, s02 = f0 * f2;
            float rq  = __builtin_amdgcn_rcpf(s01 * f2);
            a0 = __builtin_fmaf(-P0.w, rq * s12, a0);
            a1 = __builtin_fmaf(-P1.w, rq * s02, a1);
            a2 = __builtin_fmaf(-P2.w, rq * s01, a2);
        }
    }
    red[tid] = a0 + a1 + a2;
    __syncthreads();
    if (tid < 64) {
        float r = red[tid] + red[tid + 64] + red[tid + 128] + red[tid + 192];
        int o = ((b * 32 + co) << 10) + (chunk << 6) + tid;
        out[o] = r + K0[co];
    }
}

extern "C" void kernel_launch(void* const* d_in, const int* in_sizes, int n_in,
                              void* d_out, int out_size, void* d_ws, size_t ws_size,
                              hipStream_t stream) {
    const float* x        = (const float*)d_in[0];
    const float* k        = (const float*)d_in[1];
    const float* Ec       = (const float*)d_in[2];
    const float* Ps       = (const float*)d_in[3];
    const float* bias     = (const float*)d_in[4];
    const float* coef     = (const float*)d_in[5];
    const float* out_bias = (const float*)d_in[6];
    float* out = (float*)d_out;

    float2* xe = (float2*)d_ws;
    float4* P4 = (float4*)((char*)d_ws + 591872u);
    float*  K0 = (float*)((char*)d_ws + 813056u);

    prep_kernel<<<351, 256, 0, stream>>>(x, k, Ec, Ps, bias, coef, out_bias, xe, P4, K0);
    main_kernel<<<2048, 256, 0, stream>>>(xe, P4, K0, out);
}

// Round 7
// 28.573 us; speedup vs baseline: 1.3462x; 1.3462x over previous
//
#include <hip/hip_runtime.h>

#define LOG2E 1.4426950408889634f
#define C1 (10.0f * LOG2E)

// Single fused kernel. grid 2048 = (b:4, co:32, chunk:16 of 2 output rows).
// 256 threads = 4 waves; wave w owns ci in [4w, 4w+4).
// Per block: stage (x, E1=exp2(C1*x)) slab for its 4 padded rows x 16 ci in LDS,
// derive co's 432 params {T1=exp2(C1*Ec), Zk=2*LOG2E*k, A=Zk*Ec, W2=2*Ps*coef} in LDS,
// fold K0 = sum coef*(Ps+bias) into a block reduction. No workspace, no prep kernel.
__global__ __launch_bounds__(256, 6) void fused_kernel(
    const float* __restrict__ x, const float* __restrict__ kk,
    const float* __restrict__ Ec, const float* __restrict__ Ps,
    const float* __restrict__ bias, const float* __restrict__ coef,
    const float* __restrict__ out_bias, float* __restrict__ out) {
    __shared__ float2 sX[2176];   // [ci:16][r:4][c:34]
    __shared__ float4 sP[432];    // [ci:16][j:9][nb:3]
    __shared__ float  red[256];
    __shared__ float  wK0[4];

    const int bid = blockIdx.x, tid = threadIdx.x;
    const int chunk = bid & 15;
    const int co    = (bid >> 4) & 31;
    const int b     = bid >> 9;

    // ---- stage x / E1 slab (rows chunk*2-1 .. chunk*2+2, cols -1..32) ----
    for (int t = tid; t < 2176; t += 256) {
        int ci  = t / 136;
        int rem = t - ci * 136;
        int r   = rem / 34;
        int c   = rem - r * 34;
        int row = chunk * 2 + r - 1;
        int col = c - 1;
        float xv = 0.f;
        if ((unsigned)row < 32u && (unsigned)col < 32u)
            xv = x[((b * 16 + ci) << 10) + (row << 5) + col];
        sX[t] = make_float2(xv, __builtin_amdgcn_exp2f(C1 * xv));
    }

    // ---- derive this co's params; accumulate K0 partial ----
    float kpart = 0.f;
    for (int t = tid; t < 432; t += 256) {
        int ci = t / 27;
        int r2 = t - ci * 27;
        int j  = r2 / 3;
        int nb = r2 - j * 3;
        int i  = co * 432 + ci * 27 + nb * 9 + j;   // input layout [ci][nb][j]
        float e  = Ec[i];
        float zk = 2.0f * LOG2E * kk[i];
        float ps = Ps[i], cf = coef[i];
        sP[t] = make_float4(__builtin_amdgcn_exp2f(C1 * e), zk, zk * e, 2.0f * ps * cf);
        kpart += cf * (ps + bias[i]);
    }
    #pragma unroll
    for (int off = 32; off >= 1; off >>= 1) kpart += __shfl_down(kpart, off, 64);
    if ((tid & 63) == 0) wK0[tid >> 6] = kpart;
    __syncthreads();

    // ---- main compute ----
    const int px = tid & 63;
    const int w  = px & 31;
    const int hr = px >> 5;                 // 0..1
    const int cb = (tid >> 6) << 2;

    float a0 = 0.f, a1 = 0.f, a2 = 0.f;
    #pragma unroll
    for (int i = 0; i < 4; ++i) {
        const float2* xw = &sX[(cb + i) * 136 + hr * 34 + w];
        float2 X[9];
        #pragma unroll
        for (int j = 0; j < 9; ++j)
            X[j] = xw[(j / 3) * 34 + (j % 3)];
        const float4* pc = &sP[(cb + i) * 27];
        #pragma unroll
        for (int j = 0; j < 9; ++j) {
            const float xv = X[j].x, E1 = X[j].y;
            const float4 P0 = pc[j * 3 + 0];
            const float4 P1 = pc[j * 3 + 1];
            const float4 P2 = pc[j * 3 + 2];
            float cn0 = __builtin_amdgcn_rcpf(__builtin_fmaf(E1, P0.x, 1.f));
            float cn1 = __builtin_amdgcn_rcpf(__builtin_fmaf(E1, P1.x, 1.f));
            float cn2 = __builtin_amdgcn_rcpf(__builtin_fmaf(E1, P2.x, 1.f));
            float t0 = __builtin_fmaf(P0.y, xv, P0.z);
            float t1 = __builtin_fmaf(P1.y, xv, P1.z);
            float t2 = __builtin_fmaf(P2.y, xv, P2.z);
            float u0 = __builtin_fmaf(-0.2f * P0.z, cn0, t0);
            float u1 = __builtin_fmaf(-0.2f * P1.z, cn1, t1);
            float u2 = __builtin_fmaf(-0.2f * P2.z, cn2, t2);
            float e0 = __builtin_amdgcn_exp2f(u0);
            float e1 = __builtin_amdgcn_exp2f(u1);
            float e2 = __builtin_amdgcn_exp2f(u2);
            float r0 = __builtin_amdgcn_rcpf(1.f + e0);
            float r1 = __builtin_amdgcn_rcpf(1.f + e1);
            float r2 = __builtin_amdgcn_rcpf(1.f + e2);
            a0 = __builtin_fmaf(-P0.w, r0, a0);
            a1 = __builtin_fmaf(-P1.w, r1, a1);
            a2 = __builtin_fmaf(-P2.w, r2, a2);
        }
    }
    red[tid] = a0 + a1 + a2;
    __syncthreads();
    if (tid < 64) {
        float r = red[tid] + red[tid + 64] + red[tid + 128] + red[tid + 192];
        float k0 = wK0[0] + wK0[1] + wK0[2] + wK0[3] + out_bias[co];
        int o = ((b * 32 + co) << 10) + (chunk << 6) + tid;
        out[o] = r + k0;
    }
}

extern "C" void kernel_launch(void* const* d_in, const int* in_sizes, int n_in,
                              void* d_out, int out_size, void* d_ws, size_t ws_size,
                              hipStream_t stream) {
    const float* x        = (const float*)d_in[0];
    const float* k        = (const float*)d_in[1];
    const float* Ec       = (const float*)d_in[2];
    const float* Ps       = (const float*)d_in[3];
    const float* bias     = (const float*)d_in[4];
    const float* coef     = (const float*)d_in[5];
    const float* out_bias = (const float*)d_in[6];
    float* out = (float*)d_out;

    fused_kernel<<<2048, 256, 0, stream>>>(x, k, Ec, Ps, bias, coef, out_bias, out);
}